// Round 14
// baseline (10264.610 us; speedup 1.0000x reference)
//
#include <hip/hip_runtime.h>
#include <hip/hip_bf16.h>

typedef __attribute__((ext_vector_type(4))) float  fvec4;
typedef __attribute__((ext_vector_type(8))) short  svec8;    // 8 bf16 (4 VGPRs), MFMA A/B frag
typedef __attribute__((ext_vector_type(8))) unsigned short usvec8;
typedef __attribute__((ext_vector_type(4))) unsigned short usvec4;
typedef __attribute__((ext_vector_type(2))) unsigned int   uivec2;
typedef __attribute__((ext_vector_type(4))) unsigned int   uivec4;

#define MFMA16 __builtin_amdgcn_mfma_f32_16x16x32_bf16

static __device__ __forceinline__ unsigned short f2bf(float f) {
    __hip_bfloat16 h = __float2bfloat16(f);
    return __builtin_bit_cast(unsigned short, h);
}
static __device__ __forceinline__ float bf2f(unsigned short u) {
    unsigned int v = ((unsigned int)u) << 16;
    return __builtin_bit_cast(float, v);
}

// ---------------- fp32 -> bf16 convert ----------------
__global__ void cvt_kernel(const float* __restrict__ in, unsigned short* __restrict__ out, int n4) {
    int stride = gridDim.x * blockDim.x;
    for (int i = blockIdx.x * blockDim.x + threadIdx.x; i < n4; i += stride) {
        fvec4 v = ((const fvec4*)in)[i];
        usvec4 u;
        u[0] = f2bf(v[0]); u[1] = f2bf(v[1]); u[2] = f2bf(v[2]); u[3] = f2bf(v[3]);
        ((usvec4*)out)[i] = u;
    }
}

// ---------------- GEMM: out[m][n] = sum_k lhs[m][k] * rhs[n][k], K=N=512 ----------------
// (unchanged since round 1 — verified)
template<bool LHS_F32_PERM, bool OUT_PERM>
__global__ __launch_bounds__(256)
void gemm512(const void* __restrict__ lhsv, const unsigned short* __restrict__ rhs,
             void* __restrict__ outv)
{
    __shared__ __align__(16) unsigned short smA[64 * 72];
    __shared__ __align__(16) unsigned short smB[64 * 72];
    const int tid = threadIdx.x;
    const int m0 = blockIdx.x * 64;
    const int n0 = blockIdx.y * 64;
    const int w = tid >> 6, l = tid & 63;
    const int g = l >> 4, r16 = l & 15;
    const int wm = (w >> 1) * 32, wn = (w & 1) * 32;
    const int ri = tid >> 2;
    const int kseg = (tid & 3) * 16;

    fvec4 acc[2][2] = {};

    for (int k0 = 0; k0 < 512; k0 += 64) {
        if (LHS_F32_PERM) {
            const float* x = (const float*)lhsv;
            int m = m0 + ri;
            size_t base = ((size_t)(m & 15) * 4096 + (size_t)(m >> 4)) * 512 + k0 + kseg;
            usvec8 o0, o1;
            fvec4 v0 = *(const fvec4*)(x + base + 0);
            fvec4 v1 = *(const fvec4*)(x + base + 4);
            fvec4 v2 = *(const fvec4*)(x + base + 8);
            fvec4 v3 = *(const fvec4*)(x + base + 12);
            o0[0]=f2bf(v0[0]); o0[1]=f2bf(v0[1]); o0[2]=f2bf(v0[2]); o0[3]=f2bf(v0[3]);
            o0[4]=f2bf(v1[0]); o0[5]=f2bf(v1[1]); o0[6]=f2bf(v1[2]); o0[7]=f2bf(v1[3]);
            o1[0]=f2bf(v2[0]); o1[1]=f2bf(v2[1]); o1[2]=f2bf(v2[2]); o1[3]=f2bf(v2[3]);
            o1[4]=f2bf(v3[0]); o1[5]=f2bf(v3[1]); o1[6]=f2bf(v3[2]); o1[7]=f2bf(v3[3]);
            *(usvec8*)(smA + ri * 72 + kseg)     = o0;
            *(usvec8*)(smA + ri * 72 + kseg + 8) = o1;
        } else {
            const unsigned short* s = (const unsigned short*)lhsv;
            size_t base = (size_t)(m0 + ri) * 512 + k0 + kseg;
            *(usvec8*)(smA + ri * 72 + kseg)     = *(const usvec8*)(s + base);
            *(usvec8*)(smA + ri * 72 + kseg + 8) = *(const usvec8*)(s + base + 8);
        }
        {
            size_t base = (size_t)(n0 + ri) * 512 + k0 + kseg;
            *(usvec8*)(smB + ri * 72 + kseg)     = *(const usvec8*)(rhs + base);
            *(usvec8*)(smB + ri * 72 + kseg + 8) = *(const usvec8*)(rhs + base + 8);
        }
        __syncthreads();
        #pragma unroll
        for (int kt = 0; kt < 2; ++kt) {
            svec8 a0 = *(const svec8*)(smA + (wm +      r16) * 72 + 32 * kt + 8 * g);
            svec8 a1 = *(const svec8*)(smA + (wm + 16 + r16) * 72 + 32 * kt + 8 * g);
            svec8 b0 = *(const svec8*)(smB + (wn +      r16) * 72 + 32 * kt + 8 * g);
            svec8 b1 = *(const svec8*)(smB + (wn + 16 + r16) * 72 + 32 * kt + 8 * g);
            acc[0][0] = MFMA16(a0, b0, acc[0][0], 0, 0, 0);
            acc[0][1] = MFMA16(a0, b1, acc[0][1], 0, 0, 0);
            acc[1][0] = MFMA16(a1, b0, acc[1][0], 0, 0, 0);
            acc[1][1] = MFMA16(a1, b1, acc[1][1], 0, 0, 0);
        }
        __syncthreads();
    }
    #pragma unroll
    for (int mt = 0; mt < 2; ++mt)
    #pragma unroll
    for (int nt = 0; nt < 2; ++nt)
    #pragma unroll
    for (int r = 0; r < 4; ++r) {
        int m = m0 + wm + 16 * mt + 4 * g + r;
        int n = n0 + wn + 16 * nt + r16;
        float v = acc[mt][nt][r];
        if (OUT_PERM) {
            float* out = (float*)outv;
            out[((size_t)(m & 15) * 4096 + (size_t)(m >> 4)) * 512 + n] = v;
        } else {
            unsigned short* out = (unsigned short*)outv;
            out[(size_t)m * 512 + n] = f2bf(v);
        }
    }
}

// ---------------- recurrence: ONE workgroup, 8 waves (2/SIMD), intrinsics + prefetch ------
// Round-14 = round-13 (proven correct, 5,950us) + ONE change: manual depth-1 LDS
// prefetch inside the MFMA train. Loads for kt+1 issue BEFORE kt's MFMAs (2-slot
// static rotation), so each kt's MFMAs never wait on their own ds_read latency —
// which r13's counters showed aligns across barrier-synced co-waves (TLP can't
// hide it). sched_barrier(0) kept per kt to bound scheduler hoisting.
// Register tally at 2 waves/SIMD (256 unified/wave): af 192 (compiler splits
// AGPR/arch) + acc 16 + sbv 8 + s3a 8 + bq 8 + addr/misc ~20 = ~252 <= 256.
// All MFMAs pure __builtin (r11/r12's inline-asm-at-cap corruption class excluded).
// Wave w owns n_out [64w, 64w+64), FULL k; A-split mt0..2 -> regs, mt3 -> LDS.
// Single barrier/step (st[2] dbuf). bq decoded transiently inside EP.
// Mappings (verified rounds 2-13, absmax 0.03125):
//   A-frag: lane l -> m = l&15, k = 32kt + 8(l>>4) + e
//   B-frag: lane l -> n = l&15 (batch), k = 32kt + 8(l>>4) + e
//   C/D:    lane l -> n = l&15 (batch), m = 4(l>>4) + reg
#define RT 4096

#define LDSB(KT) (*(const svec8*)(stp + ((64 * (KT) + 16 * g) ^ swz)))
#define LDSA3(KT) (*(const svec8*)(ldsA + ((w * 16 + (KT)) << 9) + l * 8))

// kt 0..14: prefetch kt+1 into slot (KT+1)&1, consume slot KT&1, 4 intrinsic MFMAs
#define KTSTEP(KT) do { \
    sbv[((KT) + 1) & 1] = LDSB((KT) + 1); \
    s3a[((KT) + 1) & 1] = LDSA3((KT) + 1); \
    svec8 sc = sbv[(KT) & 1]; \
    acc[0] = MFMA16(af[KT][0], sc, acc[0], 0, 0, 0); \
    acc[1] = MFMA16(af[KT][1], sc, acc[1], 0, 0, 0); \
    acc[2] = MFMA16(af[KT][2], sc, acc[2], 0, 0, 0); \
    acc[3] = MFMA16(s3a[(KT) & 1], sc, acc[3], 0, 0, 0); \
    __builtin_amdgcn_sched_barrier(0); \
} while (0)

// kt 15: no prefetch
#define KTSTEP15() do { \
    svec8 sc = sbv[1]; \
    acc[0] = MFMA16(af[15][0], sc, acc[0], 0, 0, 0); \
    acc[1] = MFMA16(af[15][1], sc, acc[1], 0, 0, 0); \
    acc[2] = MFMA16(af[15][2], sc, acc[2], 0, 0, 0); \
    acc[3] = MFMA16(s3a[1],    sc, acc[3], 0, 0, 0); \
    __builtin_amdgcn_sched_barrier(0); \
} while (0)

// epilogue one mt: +bx (transient decode), relu, cvt_pk, ds_write st[q]
#define EP(MT) do { \
    unsigned long long _u = bq[MT]; \
    float _f0 = fmaxf(acc[MT][0] + bf2f((unsigned short)( _u        & 0xffffu)), 0.0f); \
    float _f1 = fmaxf(acc[MT][1] + bf2f((unsigned short)((_u >> 16) & 0xffffu)), 0.0f); \
    float _f2 = fmaxf(acc[MT][2] + bf2f((unsigned short)((_u >> 32) & 0xffffu)), 0.0f); \
    float _f3 = fmaxf(acc[MT][3] + bf2f((unsigned short)((_u >> 48) & 0xffffu)), 0.0f); \
    unsigned int _plo, _phi; \
    asm("v_cvt_pk_bf16_f32 %0, %1, %2" : "=v"(_plo) : "v"(_f0), "v"(_f1)); \
    asm("v_cvt_pk_bf16_f32 %0, %1, %2" : "=v"(_phi) : "v"(_f2), "v"(_f3)); \
    uivec2 _ov; _ov[0] = _plo; _ov[1] = _phi; \
    *(uivec2*)(stq + ((2 * (nbase + 16 * (MT) + 4 * g)) ^ swz)) = _ov; \
} while (0)

__global__ __launch_bounds__(512, 2)
void recur1cu_kernel(const unsigned short* __restrict__ Abf,   // [512][512] bf16, A[n][k]
                     const unsigned short* __restrict__ bx,    // [65536][512] bf16, row = t*16+b
                     unsigned short* __restrict__ states)      // [65536][512] bf16, row = t*16+b
{
    __shared__ __align__(16) unsigned short st[2][16 * 512];     // 32 KB state dbuf, XOR-swizzled
    __shared__ __align__(16) unsigned short ldsA[8 * 16 * 512];  // 128 KB: [w][kt][frag 1KB], mt3
    const int tid = threadIdx.x;
    const int w = tid >> 6, l = tid & 63;
    const int g = l >> 4, r16 = l & 15;
    const int nbase = w * 64;
    const int swz = (r16 & 7) << 4;

    // ---- stage A mt=3 into LDS, fragment-linear ----
    #pragma unroll
    for (int kt = 0; kt < 16; ++kt) {
        usvec8 v = *(const usvec8*)(Abf + (size_t)(nbase + 48 + r16) * 512 + 32 * kt + 8 * g);
        *(usvec8*)(ldsA + ((w * 16 + kt) << 9) + l * 8) = v;
    }

    // ---- preload A mt=0..2 into plain registers: 48 frags = 192 regs ----
    svec8 af[16][3];
    #pragma unroll
    for (int kt = 0; kt < 16; ++kt)
        #pragma unroll
        for (int mt = 0; mt < 3; ++mt)
            af[kt][mt] = *(const svec8*)(Abf + (size_t)(nbase + 16 * mt + r16) * 512
                                         + 32 * kt + 8 * g);

    // ---- t = 0: state0 = relu(bx[0]) -> st[0] own 64 cols ----
    {
        const unsigned short* bp = bx + (size_t)r16 * 512 + nbase + 4 * g;
        char* st0 = (char*)&st[0][0] + r16 * 1024;
        #pragma unroll
        for (int mt = 0; mt < 4; ++mt) {
            unsigned long long u = *(const unsigned long long*)(bp + 16 * mt);
            float f0 = fmaxf(bf2f((unsigned short)( u        & 0xffffu)), 0.0f);
            float f1 = fmaxf(bf2f((unsigned short)((u >> 16) & 0xffffu)), 0.0f);
            float f2 = fmaxf(bf2f((unsigned short)((u >> 32) & 0xffffu)), 0.0f);
            float f3 = fmaxf(bf2f((unsigned short)((u >> 48) & 0xffffu)), 0.0f);
            unsigned int plo, phi;
            asm("v_cvt_pk_bf16_f32 %0, %1, %2" : "=v"(plo) : "v"(f0), "v"(f1));
            asm("v_cvt_pk_bf16_f32 %0, %1, %2" : "=v"(phi) : "v"(f2), "v"(f3));
            uivec2 ov; ov[0] = plo; ov[1] = phi;
            *(uivec2*)(st0 + ((2 * (nbase + 16 * mt + 4 * g)) ^ swz)) = ov;
        }
    }
    __syncthreads();

    // export lane mapping: wave w exports state rows {2w, 2w+1}; 32 lanes x 16B per half-row
    const int erow = 2 * w + (l >> 5);
    const int eswz = (erow & 7) << 4;
    const int ecol = (l & 31) * 16;

    #pragma unroll 1
    for (int t = 1; t < RT; ++t) {
        const char* stbase_p = (const char*)&st[(t - 1) & 1][0];
        char* stq = (char*)&st[t & 1][0] + r16 * 1024;

        // A) coalesced export of state_{t-1}; store drain overlaps MFMA region
        {
            const char* sp = stbase_p + erow * 1024;
            char* gp = (char*)states + ((size_t)(t - 1) * 16 + erow) * 1024 + ecol;
            #pragma unroll
            for (int jj = 0; jj < 2; ++jj) {
                uivec4 v = *(const uivec4*)(sp + ((ecol + 512 * jj) ^ eswz));
                *(uivec4*)(gp + 512 * jj) = v;
            }
        }

        // B) bx[t] loads (decoded transiently inside EP)
        unsigned long long bq[4];
        {
            const unsigned short* bp = bx + ((size_t)t * 16 + r16) * 512 + nbase + 4 * g;
            #pragma unroll
            for (int mt = 0; mt < 4; ++mt)
                bq[mt] = *(const unsigned long long*)(bp + 16 * mt);
        }

        // C) MFMA train: depth-1 prefetched, 16 kt x 4 intrinsic MFMAs, reads st[p]
        fvec4 acc[4];
        #pragma unroll
        for (int mt = 0; mt < 4; ++mt) acc[mt] = fvec4{0.f, 0.f, 0.f, 0.f};

        const char* stp = stbase_p + r16 * 1024;
        svec8 sbv[2], s3a[2];
        sbv[0] = LDSB(0);
        s3a[0] = LDSA3(0);
        KTSTEP(0);  KTSTEP(1);  KTSTEP(2);  KTSTEP(3);
        KTSTEP(4);  KTSTEP(5);  KTSTEP(6);  KTSTEP(7);
        KTSTEP(8);  KTSTEP(9);  KTSTEP(10); KTSTEP(11);
        KTSTEP(12); KTSTEP(13); KTSTEP(14); KTSTEP15();

        // D) epilogue: + bx, relu, cvt_pk, write st[q] own cols
        EP(0); EP(1); EP(2); EP(3);

        __syncthreads();   // st[q] complete; st[p] free for overwrite next iteration
    }

    // ---- final export: state_{RT-1} from st[(RT-1)&1] ----
    {
        const char* sp = (const char*)&st[(RT - 1) & 1][0] + erow * 1024;
        char* gp = (char*)states + ((size_t)(RT - 1) * 16 + erow) * 1024 + ecol;
        #pragma unroll
        for (int jj = 0; jj < 2; ++jj) {
            uivec4 v = *(const uivec4*)(sp + ((ecol + 512 * jj) ^ eswz));
            *(uivec4*)(gp + 512 * jj) = v;
        }
    }
}

extern "C" void kernel_launch(void* const* d_in, const int* in_sizes, int n_in,
                              void* d_out, int out_size, void* d_ws, size_t ws_size,
                              hipStream_t stream) {
    const float* x = (const float*)d_in[0];   // [16][4096][512]
    const float* A = (const float*)d_in[1];   // [512][512]
    const float* B = (const float*)d_in[2];   // [512][512]
    const float* C = (const float*)d_in[3];   // [512][512]
    float* out = (float*)d_out;               // [16][4096][512]

    char* ws = (char*)d_ws;
    unsigned short* Abf = (unsigned short*)(ws + 0);                          // 512KB
    unsigned short* Bbf = (unsigned short*)(ws + (size_t)(1 << 19));          // 512KB
    unsigned short* Cbf = (unsigned short*)(ws + (size_t)(2 << 19));          // 512KB
    unsigned short* bx  = (unsigned short*)(ws + (size_t)(4 << 19));          // 64MB: [65536][512] bf16
    unsigned short* states = (unsigned short*)(ws + (size_t)(4 << 19) + ((size_t)1 << 26)); // 64MB

    cvt_kernel<<<64, 256, 0, stream>>>(A, Abf, 512 * 512 / 4);
    cvt_kernel<<<64, 256, 0, stream>>>(B, Bbf, 512 * 512 / 4);
    cvt_kernel<<<64, 256, 0, stream>>>(C, Cbf, 512 * 512 / 4);

    dim3 grid(1024, 8);
    // bx[t*16+b][n] = sum_d x[b][t][d] * B[n][d]
    gemm512<true, false><<<grid, 256, 0, stream>>>((const void*)x, Bbf, (void*)bx);
    // sequential recurrence on one CU, 8 waves, states[t*16+b][n]
    recur1cu_kernel<<<1, 512, 0, stream>>>(Abf, bx, states);
    // y[b][t][j] = sum_n states[t*16+b][n] * C[j][n]
    gemm512<false, true><<<grid, 256, 0, stream>>>((const void*)states, Cbf, (void*)out);
}

// Round 15
// 8549.074 us; speedup vs baseline: 1.2007x; 1.2007x over previous
//
#include <hip/hip_runtime.h>
#include <hip/hip_bf16.h>

typedef __attribute__((ext_vector_type(4))) float  fvec4;
typedef __attribute__((ext_vector_type(8))) short  svec8;    // 8 bf16 (4 VGPRs), MFMA A/B frag
typedef __attribute__((ext_vector_type(8))) unsigned short usvec8;
typedef __attribute__((ext_vector_type(4))) unsigned short usvec4;
typedef __attribute__((ext_vector_type(2))) unsigned int   uivec2;
typedef __attribute__((ext_vector_type(4))) unsigned int   uivec4;

#define MFMA16 __builtin_amdgcn_mfma_f32_16x16x32_bf16

static __device__ __forceinline__ unsigned short f2bf(float f) {
    __hip_bfloat16 h = __float2bfloat16(f);
    return __builtin_bit_cast(unsigned short, h);
}
static __device__ __forceinline__ float bf2f(unsigned short u) {
    unsigned int v = ((unsigned int)u) << 16;
    return __builtin_bit_cast(float, v);
}

// ---------------- fp32 -> bf16 convert ----------------
__global__ void cvt_kernel(const float* __restrict__ in, unsigned short* __restrict__ out, int n4) {
    int stride = gridDim.x * blockDim.x;
    for (int i = blockIdx.x * blockDim.x + threadIdx.x; i < n4; i += stride) {
        fvec4 v = ((const fvec4*)in)[i];
        usvec4 u;
        u[0] = f2bf(v[0]); u[1] = f2bf(v[1]); u[2] = f2bf(v[2]); u[3] = f2bf(v[3]);
        ((usvec4*)out)[i] = u;
    }
}

// ---------------- GEMM: out[m][n] = sum_k lhs[m][k] * rhs[n][k], K=N=512 ----------------
// (unchanged since round 1 — verified)
template<bool LHS_F32_PERM, bool OUT_PERM>
__global__ __launch_bounds__(256)
void gemm512(const void* __restrict__ lhsv, const unsigned short* __restrict__ rhs,
             void* __restrict__ outv)
{
    __shared__ __align__(16) unsigned short smA[64 * 72];
    __shared__ __align__(16) unsigned short smB[64 * 72];
    const int tid = threadIdx.x;
    const int m0 = blockIdx.x * 64;
    const int n0 = blockIdx.y * 64;
    const int w = tid >> 6, l = tid & 63;
    const int g = l >> 4, r16 = l & 15;
    const int wm = (w >> 1) * 32, wn = (w & 1) * 32;
    const int ri = tid >> 2;
    const int kseg = (tid & 3) * 16;

    fvec4 acc[2][2] = {};

    for (int k0 = 0; k0 < 512; k0 += 64) {
        if (LHS_F32_PERM) {
            const float* x = (const float*)lhsv;
            int m = m0 + ri;
            size_t base = ((size_t)(m & 15) * 4096 + (size_t)(m >> 4)) * 512 + k0 + kseg;
            usvec8 o0, o1;
            fvec4 v0 = *(const fvec4*)(x + base + 0);
            fvec4 v1 = *(const fvec4*)(x + base + 4);
            fvec4 v2 = *(const fvec4*)(x + base + 8);
            fvec4 v3 = *(const fvec4*)(x + base + 12);
            o0[0]=f2bf(v0[0]); o0[1]=f2bf(v0[1]); o0[2]=f2bf(v0[2]); o0[3]=f2bf(v0[3]);
            o0[4]=f2bf(v1[0]); o0[5]=f2bf(v1[1]); o0[6]=f2bf(v1[2]); o0[7]=f2bf(v1[3]);
            o1[0]=f2bf(v2[0]); o1[1]=f2bf(v2[1]); o1[2]=f2bf(v2[2]); o1[3]=f2bf(v2[3]);
            o1[4]=f2bf(v3[0]); o1[5]=f2bf(v3[1]); o1[6]=f2bf(v3[2]); o1[7]=f2bf(v3[3]);
            *(usvec8*)(smA + ri * 72 + kseg)     = o0;
            *(usvec8*)(smA + ri * 72 + kseg + 8) = o1;
        } else {
            const unsigned short* s = (const unsigned short*)lhsv;
            size_t base = (size_t)(m0 + ri) * 512 + k0 + kseg;
            *(usvec8*)(smA + ri * 72 + kseg)     = *(const usvec8*)(s + base);
            *(usvec8*)(smA + ri * 72 + kseg + 8) = *(const usvec8*)(s + base + 8);
        }
        {
            size_t base = (size_t)(n0 + ri) * 512 + k0 + kseg;
            *(usvec8*)(smB + ri * 72 + kseg)     = *(const usvec8*)(rhs + base);
            *(usvec8*)(smB + ri * 72 + kseg + 8) = *(const usvec8*)(rhs + base + 8);
        }
        __syncthreads();
        #pragma unroll
        for (int kt = 0; kt < 2; ++kt) {
            svec8 a0 = *(const svec8*)(smA + (wm +      r16) * 72 + 32 * kt + 8 * g);
            svec8 a1 = *(const svec8*)(smA + (wm + 16 + r16) * 72 + 32 * kt + 8 * g);
            svec8 b0 = *(const svec8*)(smB + (wn +      r16) * 72 + 32 * kt + 8 * g);
            svec8 b1 = *(const svec8*)(smB + (wn + 16 + r16) * 72 + 32 * kt + 8 * g);
            acc[0][0] = MFMA16(a0, b0, acc[0][0], 0, 0, 0);
            acc[0][1] = MFMA16(a0, b1, acc[0][1], 0, 0, 0);
            acc[1][0] = MFMA16(a1, b0, acc[1][0], 0, 0, 0);
            acc[1][1] = MFMA16(a1, b1, acc[1][1], 0, 0, 0);
        }
        __syncthreads();
    }
    #pragma unroll
    for (int mt = 0; mt < 2; ++mt)
    #pragma unroll
    for (int nt = 0; nt < 2; ++nt)
    #pragma unroll
    for (int r = 0; r < 4; ++r) {
        int m = m0 + wm + 16 * mt + 4 * g + r;
        int n = n0 + wn + 16 * nt + r16;
        float v = acc[mt][nt][r];
        if (OUT_PERM) {
            float* out = (float*)outv;
            out[((size_t)(m & 15) * 4096 + (size_t)(m >> 4)) * 512 + n] = v;
        } else {
            unsigned short* out = (unsigned short*)outv;
            out[(size_t)m * 512 + n] = f2bf(v);
        }
    }
}

// ---------------- recurrence: ONE workgroup, 8 waves (2/SIMD), intrinsics ---------------
// Round-15 = round-13 (proven 5,950us) + register-OFFSET state prefetch + setprio:
//   - sbv[2] rotation prefetches ONLY the state stream (+8 regs). The A3 fragment is
//     the 4th MFMA's operand, so the compiler's fine-grained lgkmcnt already hides its
//     latency behind 3 MFMAs -> transient a3, no rotation slot. (r14 rotated BOTH
//     streams, +16 regs, spilled af to scratch: 10,031us. Never both.)
//   - offset: bq split 2+2 (pair 2 loads at kt8, covered by kts 8-15) -> peak live
//     pressure in first train half reduced by 4 regs.
//   - s_setprio(1) around the MFMA train (T5): 2 waves/SIMD drift within the step,
//     scheduler favors the MFMA-issuing wave. Zero register cost.
// All MFMAs pure __builtin (r11/r12 inline-asm-at-cap corruption class excluded).
// Wave w owns n_out [64w, 64w+64), FULL k; A-split mt0..2 -> regs (192), mt3 -> LDS.
// Single barrier/step (st[2] dbuf). bq decoded transiently inside EP.
// Mappings (verified rounds 2-14, absmax 0.03125):
//   A-frag: lane l -> m = l&15, k = 32kt + 8(l>>4) + e
//   B-frag: lane l -> n = l&15 (batch), k = 32kt + 8(l>>4) + e
//   C/D:    lane l -> n = l&15 (batch), m = 4(l>>4) + reg
#define RT 4096

#define LDSB(KT) (*(const svec8*)(stp + ((64 * (KT) + 16 * g) ^ swz)))
#define LDSA3(KT) (*(const svec8*)(ldsA + ((w * 16 + (KT)) << 9) + l * 8))

// kt 0..14: prefetch state kt+1 (rotation); A3 read transient (covered by 3 MFMAs)
#define KTSTEP(KT) do { \
    sbv[((KT) + 1) & 1] = LDSB((KT) + 1); \
    svec8 a3 = LDSA3(KT); \
    svec8 sc = sbv[(KT) & 1]; \
    acc[0] = MFMA16(af[KT][0], sc, acc[0], 0, 0, 0); \
    acc[1] = MFMA16(af[KT][1], sc, acc[1], 0, 0, 0); \
    acc[2] = MFMA16(af[KT][2], sc, acc[2], 0, 0, 0); \
    acc[3] = MFMA16(a3,        sc, acc[3], 0, 0, 0); \
    __builtin_amdgcn_sched_barrier(0); \
} while (0)

// kt 15: no prefetch
#define KTSTEP15() do { \
    svec8 a3 = LDSA3(15); \
    svec8 sc = sbv[1]; \
    acc[0] = MFMA16(af[15][0], sc, acc[0], 0, 0, 0); \
    acc[1] = MFMA16(af[15][1], sc, acc[1], 0, 0, 0); \
    acc[2] = MFMA16(af[15][2], sc, acc[2], 0, 0, 0); \
    acc[3] = MFMA16(a3,        sc, acc[3], 0, 0, 0); \
    __builtin_amdgcn_sched_barrier(0); \
} while (0)

// epilogue one mt: +bx (transient decode), relu, cvt_pk, ds_write st[q]
#define EP(MT, BQ) do { \
    unsigned long long _u = (BQ); \
    float _f0 = fmaxf(acc[MT][0] + bf2f((unsigned short)( _u        & 0xffffu)), 0.0f); \
    float _f1 = fmaxf(acc[MT][1] + bf2f((unsigned short)((_u >> 16) & 0xffffu)), 0.0f); \
    float _f2 = fmaxf(acc[MT][2] + bf2f((unsigned short)((_u >> 32) & 0xffffu)), 0.0f); \
    float _f3 = fmaxf(acc[MT][3] + bf2f((unsigned short)((_u >> 48) & 0xffffu)), 0.0f); \
    unsigned int _plo, _phi; \
    asm("v_cvt_pk_bf16_f32 %0, %1, %2" : "=v"(_plo) : "v"(_f0), "v"(_f1)); \
    asm("v_cvt_pk_bf16_f32 %0, %1, %2" : "=v"(_phi) : "v"(_f2), "v"(_f3)); \
    uivec2 _ov; _ov[0] = _plo; _ov[1] = _phi; \
    *(uivec2*)(stq + ((2 * (nbase + 16 * (MT) + 4 * g)) ^ swz)) = _ov; \
} while (0)

__global__ __launch_bounds__(512, 2)
void recur1cu_kernel(const unsigned short* __restrict__ Abf,   // [512][512] bf16, A[n][k]
                     const unsigned short* __restrict__ bx,    // [65536][512] bf16, row = t*16+b
                     unsigned short* __restrict__ states)      // [65536][512] bf16, row = t*16+b
{
    __shared__ __align__(16) unsigned short st[2][16 * 512];     // 32 KB state dbuf, XOR-swizzled
    __shared__ __align__(16) unsigned short ldsA[8 * 16 * 512];  // 128 KB: [w][kt][frag 1KB], mt3
    const int tid = threadIdx.x;
    const int w = tid >> 6, l = tid & 63;
    const int g = l >> 4, r16 = l & 15;
    const int nbase = w * 64;
    const int swz = (r16 & 7) << 4;

    // ---- stage A mt=3 into LDS, fragment-linear ----
    #pragma unroll
    for (int kt = 0; kt < 16; ++kt) {
        usvec8 v = *(const usvec8*)(Abf + (size_t)(nbase + 48 + r16) * 512 + 32 * kt + 8 * g);
        *(usvec8*)(ldsA + ((w * 16 + kt) << 9) + l * 8) = v;
    }

    // ---- preload A mt=0..2 into plain registers: 48 frags = 192 regs ----
    svec8 af[16][3];
    #pragma unroll
    for (int kt = 0; kt < 16; ++kt)
        #pragma unroll
        for (int mt = 0; mt < 3; ++mt)
            af[kt][mt] = *(const svec8*)(Abf + (size_t)(nbase + 16 * mt + r16) * 512
                                         + 32 * kt + 8 * g);

    // ---- t = 0: state0 = relu(bx[0]) -> st[0] own 64 cols ----
    {
        const unsigned short* bp = bx + (size_t)r16 * 512 + nbase + 4 * g;
        char* st0 = (char*)&st[0][0] + r16 * 1024;
        #pragma unroll
        for (int mt = 0; mt < 4; ++mt) {
            unsigned long long u = *(const unsigned long long*)(bp + 16 * mt);
            float f0 = fmaxf(bf2f((unsigned short)( u        & 0xffffu)), 0.0f);
            float f1 = fmaxf(bf2f((unsigned short)((u >> 16) & 0xffffu)), 0.0f);
            float f2 = fmaxf(bf2f((unsigned short)((u >> 32) & 0xffffu)), 0.0f);
            float f3 = fmaxf(bf2f((unsigned short)((u >> 48) & 0xffffu)), 0.0f);
            unsigned int plo, phi;
            asm("v_cvt_pk_bf16_f32 %0, %1, %2" : "=v"(plo) : "v"(f0), "v"(f1));
            asm("v_cvt_pk_bf16_f32 %0, %1, %2" : "=v"(phi) : "v"(f2), "v"(f3));
            uivec2 ov; ov[0] = plo; ov[1] = phi;
            *(uivec2*)(st0 + ((2 * (nbase + 16 * mt + 4 * g)) ^ swz)) = ov;
        }
    }
    __syncthreads();

    // export lane mapping: wave w exports state rows {2w, 2w+1}; 32 lanes x 16B per half-row
    const int erow = 2 * w + (l >> 5);
    const int eswz = (erow & 7) << 4;
    const int ecol = (l & 31) * 16;

    #pragma unroll 1
    for (int t = 1; t < RT; ++t) {
        const char* stbase_p = (const char*)&st[(t - 1) & 1][0];
        char* stq = (char*)&st[t & 1][0] + r16 * 1024;

        // A) coalesced export of state_{t-1}; store drain overlaps MFMA region
        {
            const char* sp = stbase_p + erow * 1024;
            char* gp = (char*)states + ((size_t)(t - 1) * 16 + erow) * 1024 + ecol;
            #pragma unroll
            for (int jj = 0; jj < 2; ++jj) {
                uivec4 v = *(const uivec4*)(sp + ((ecol + 512 * jj) ^ eswz));
                *(uivec4*)(gp + 512 * jj) = v;
            }
        }

        // B) bx[t] first half (mt 0,1); second half loads at kt8 (register-pressure offset)
        const unsigned short* bp = bx + ((size_t)t * 16 + r16) * 512 + nbase + 4 * g;
        unsigned long long bq0 = *(const unsigned long long*)(bp + 0);
        unsigned long long bq1 = *(const unsigned long long*)(bp + 16);

        // C) MFMA train: state prefetched depth-1, 16 kt x 4 intrinsic MFMAs, reads st[p]
        fvec4 acc[4];
        #pragma unroll
        for (int mt = 0; mt < 4; ++mt) acc[mt] = fvec4{0.f, 0.f, 0.f, 0.f};

        const char* stp = stbase_p + r16 * 1024;
        svec8 sbv[2];
        sbv[0] = LDSB(0);
        __builtin_amdgcn_s_setprio(1);
        KTSTEP(0);  KTSTEP(1);  KTSTEP(2);  KTSTEP(3);
        KTSTEP(4);  KTSTEP(5);  KTSTEP(6);  KTSTEP(7);
        unsigned long long bq2 = *(const unsigned long long*)(bp + 32);
        unsigned long long bq3 = *(const unsigned long long*)(bp + 48);
        KTSTEP(8);  KTSTEP(9);  KTSTEP(10); KTSTEP(11);
        KTSTEP(12); KTSTEP(13); KTSTEP(14); KTSTEP15();
        __builtin_amdgcn_s_setprio(0);

        // D) epilogue: + bx, relu, cvt_pk, write st[q] own cols
        EP(0, bq0); EP(1, bq1); EP(2, bq2); EP(3, bq3);

        __syncthreads();   // st[q] complete; st[p] free for overwrite next iteration
    }

    // ---- final export: state_{RT-1} from st[(RT-1)&1] ----
    {
        const char* sp = (const char*)&st[(RT - 1) & 1][0] + erow * 1024;
        char* gp = (char*)states + ((size_t)(RT - 1) * 16 + erow) * 1024 + ecol;
        #pragma unroll
        for (int jj = 0; jj < 2; ++jj) {
            uivec4 v = *(const uivec4*)(sp + ((ecol + 512 * jj) ^ eswz));
            *(uivec4*)(gp + 512 * jj) = v;
        }
    }
}

extern "C" void kernel_launch(void* const* d_in, const int* in_sizes, int n_in,
                              void* d_out, int out_size, void* d_ws, size_t ws_size,
                              hipStream_t stream) {
    const float* x = (const float*)d_in[0];   // [16][4096][512]
    const float* A = (const float*)d_in[1];   // [512][512]
    const float* B = (const float*)d_in[2];   // [512][512]
    const float* C = (const float*)d_in[3];   // [512][512]
    float* out = (float*)d_out;               // [16][4096][512]

    char* ws = (char*)d_ws;
    unsigned short* Abf = (unsigned short*)(ws + 0);                          // 512KB
    unsigned short* Bbf = (unsigned short*)(ws + (size_t)(1 << 19));          // 512KB
    unsigned short* Cbf = (unsigned short*)(ws + (size_t)(2 << 19));          // 512KB
    unsigned short* bx  = (unsigned short*)(ws + (size_t)(4 << 19));          // 64MB: [65536][512] bf16
    unsigned short* states = (unsigned short*)(ws + (size_t)(4 << 19) + ((size_t)1 << 26)); // 64MB

    cvt_kernel<<<64, 256, 0, stream>>>(A, Abf, 512 * 512 / 4);
    cvt_kernel<<<64, 256, 0, stream>>>(B, Bbf, 512 * 512 / 4);
    cvt_kernel<<<64, 256, 0, stream>>>(C, Cbf, 512 * 512 / 4);

    dim3 grid(1024, 8);
    // bx[t*16+b][n] = sum_d x[b][t][d] * B[n][d]
    gemm512<true, false><<<grid, 256, 0, stream>>>((const void*)x, Bbf, (void*)bx);
    // sequential recurrence on one CU, 8 waves, states[t*16+b][n]
    recur1cu_kernel<<<1, 512, 0, stream>>>(Abf, bx, states);
    // y[b][t][j] = sum_n states[t*16+b][n] * C[j][n]
    gemm512<false, true><<<grid, 256, 0, stream>>>((const void*)states, Cbf, (void*)out);
}

// Round 16
// 6195.735 us; speedup vs baseline: 1.6567x; 1.3798x over previous
//
#include <hip/hip_runtime.h>
#include <hip/hip_bf16.h>

typedef __attribute__((ext_vector_type(4))) float  fvec4;
typedef __attribute__((ext_vector_type(8))) short  svec8;    // 8 bf16 (4 VGPRs), MFMA A/B frag
typedef __attribute__((ext_vector_type(8))) unsigned short usvec8;
typedef __attribute__((ext_vector_type(4))) unsigned short usvec4;
typedef __attribute__((ext_vector_type(2))) unsigned int   uivec2;
typedef __attribute__((ext_vector_type(4))) unsigned int   uivec4;

#define MFMA16 __builtin_amdgcn_mfma_f32_16x16x32_bf16

static __device__ __forceinline__ unsigned short f2bf(float f) {
    __hip_bfloat16 h = __float2bfloat16(f);
    return __builtin_bit_cast(unsigned short, h);
}
static __device__ __forceinline__ float bf2f(unsigned short u) {
    unsigned int v = ((unsigned int)u) << 16;
    return __builtin_bit_cast(float, v);
}

// ---------------- fp32 -> bf16 convert ----------------
__global__ void cvt_kernel(const float* __restrict__ in, unsigned short* __restrict__ out, int n4) {
    int stride = gridDim.x * blockDim.x;
    for (int i = blockIdx.x * blockDim.x + threadIdx.x; i < n4; i += stride) {
        fvec4 v = ((const fvec4*)in)[i];
        usvec4 u;
        u[0] = f2bf(v[0]); u[1] = f2bf(v[1]); u[2] = f2bf(v[2]); u[3] = f2bf(v[3]);
        ((usvec4*)out)[i] = u;
    }
}

// ---------------- GEMM: out[m][n] = sum_k lhs[m][k] * rhs[n][k], K=N=512 ----------------
// (unchanged since round 1 — verified)
template<bool LHS_F32_PERM, bool OUT_PERM>
__global__ __launch_bounds__(256)
void gemm512(const void* __restrict__ lhsv, const unsigned short* __restrict__ rhs,
             void* __restrict__ outv)
{
    __shared__ __align__(16) unsigned short smA[64 * 72];
    __shared__ __align__(16) unsigned short smB[64 * 72];
    const int tid = threadIdx.x;
    const int m0 = blockIdx.x * 64;
    const int n0 = blockIdx.y * 64;
    const int w = tid >> 6, l = tid & 63;
    const int g = l >> 4, r16 = l & 15;
    const int wm = (w >> 1) * 32, wn = (w & 1) * 32;
    const int ri = tid >> 2;
    const int kseg = (tid & 3) * 16;

    fvec4 acc[2][2] = {};

    for (int k0 = 0; k0 < 512; k0 += 64) {
        if (LHS_F32_PERM) {
            const float* x = (const float*)lhsv;
            int m = m0 + ri;
            size_t base = ((size_t)(m & 15) * 4096 + (size_t)(m >> 4)) * 512 + k0 + kseg;
            usvec8 o0, o1;
            fvec4 v0 = *(const fvec4*)(x + base + 0);
            fvec4 v1 = *(const fvec4*)(x + base + 4);
            fvec4 v2 = *(const fvec4*)(x + base + 8);
            fvec4 v3 = *(const fvec4*)(x + base + 12);
            o0[0]=f2bf(v0[0]); o0[1]=f2bf(v0[1]); o0[2]=f2bf(v0[2]); o0[3]=f2bf(v0[3]);
            o0[4]=f2bf(v1[0]); o0[5]=f2bf(v1[1]); o0[6]=f2bf(v1[2]); o0[7]=f2bf(v1[3]);
            o1[0]=f2bf(v2[0]); o1[1]=f2bf(v2[1]); o1[2]=f2bf(v2[2]); o1[3]=f2bf(v2[3]);
            o1[4]=f2bf(v3[0]); o1[5]=f2bf(v3[1]); o1[6]=f2bf(v3[2]); o1[7]=f2bf(v3[3]);
            *(usvec8*)(smA + ri * 72 + kseg)     = o0;
            *(usvec8*)(smA + ri * 72 + kseg + 8) = o1;
        } else {
            const unsigned short* s = (const unsigned short*)lhsv;
            size_t base = (size_t)(m0 + ri) * 512 + k0 + kseg;
            *(usvec8*)(smA + ri * 72 + kseg)     = *(const usvec8*)(s + base);
            *(usvec8*)(smA + ri * 72 + kseg + 8) = *(const usvec8*)(s + base + 8);
        }
        {
            size_t base = (size_t)(n0 + ri) * 512 + k0 + kseg;
            *(usvec8*)(smB + ri * 72 + kseg)     = *(const usvec8*)(rhs + base);
            *(usvec8*)(smB + ri * 72 + kseg + 8) = *(const usvec8*)(rhs + base + 8);
        }
        __syncthreads();
        #pragma unroll
        for (int kt = 0; kt < 2; ++kt) {
            svec8 a0 = *(const svec8*)(smA + (wm +      r16) * 72 + 32 * kt + 8 * g);
            svec8 a1 = *(const svec8*)(smA + (wm + 16 + r16) * 72 + 32 * kt + 8 * g);
            svec8 b0 = *(const svec8*)(smB + (wn +      r16) * 72 + 32 * kt + 8 * g);
            svec8 b1 = *(const svec8*)(smB + (wn + 16 + r16) * 72 + 32 * kt + 8 * g);
            acc[0][0] = MFMA16(a0, b0, acc[0][0], 0, 0, 0);
            acc[0][1] = MFMA16(a0, b1, acc[0][1], 0, 0, 0);
            acc[1][0] = MFMA16(a1, b0, acc[1][0], 0, 0, 0);
            acc[1][1] = MFMA16(a1, b1, acc[1][1], 0, 0, 0);
        }
        __syncthreads();
    }
    #pragma unroll
    for (int mt = 0; mt < 2; ++mt)
    #pragma unroll
    for (int nt = 0; nt < 2; ++nt)
    #pragma unroll
    for (int r = 0; r < 4; ++r) {
        int m = m0 + wm + 16 * mt + 4 * g + r;
        int n = n0 + wn + 16 * nt + r16;
        float v = acc[mt][nt][r];
        if (OUT_PERM) {
            float* out = (float*)outv;
            out[((size_t)(m & 15) * 4096 + (size_t)(m >> 4)) * 512 + n] = v;
        } else {
            unsigned short* out = (unsigned short*)outv;
            out[(size_t)m * 512 + n] = f2bf(v);
        }
    }
}

// ---------------- recurrence: ONE workgroup, 8 waves (2/SIMD), PURE INTRINSICS -----------
// Round-16 = EXACT revert to round-13, the measured optimum (recur 5,950us, total
// 6,203us, absmax 0.03125). Post-r13 experiments, all falsified:
//   r14 (+16 rotation regs):        10,031us — arch regs hard-capped at 128 by the
//                                   compiler's 128/128 arch/AGPR split; spilled af.
//   r15 (+8 regs, setprio, split):   8,300us — prefetch-order bug (sb(kt+1) issued
//                                   before a3(kt) forces full lgkmcnt drain each kt)
//                                   + setprio serializes barrier-synced co-wave EPs.
//   r10 (phase rotation, 4-wave):    neutral — EP chain is a dependency chain, not
//                                   an issue-slot problem.
//   r11/r12 (inline-asm MFMA at register cap): WRONG RESULTS — excluded as a class.
// r13 sits exactly at the register-budget boundary; every added live register spills,
// and zero-register scheduling variants measured neutral-to-negative. Step model:
// 3,487 cyc = 2,048 MFMA-issue floor (128 MFMA/SIMD x 16 cyc, measured via MfmaUtil)
// + ~1,440 cyc ds-latency/EP/barrier not hideable within the register budget.
// Structure: wave w owns n_out [64w, 64w+64), FULL k; 64 intrinsic MFMAs/wave/step.
// A-split: mt0..2 -> registers (192; compiler places 128 in AGPR + 64 arch),
// mt3 -> LDS frag-linear (16KB/wave x 8 = 128KB). LDS total 160KB exactly.
// Single barrier/step (st[2] dbuf). bq decoded transiently inside EP.
// Mappings (verified rounds 2-15, absmax 0.03125):
//   A-frag: lane l -> m = l&15, k = 32kt + 8(l>>4) + e
//   B-frag: lane l -> n = l&15 (batch), k = 32kt + 8(l>>4) + e
//   C/D:    lane l -> n = l&15 (batch), m = 4(l>>4) + reg
#define RT 4096

// one kt: 2 LDS loads + 4 intrinsic MFMAs; sched_barrier bounds scheduling region
#define KTSTEP(KT) do { \
    svec8 sb = *(const svec8*)(stp + ((64 * (KT) + 16 * g) ^ swz)); \
    svec8 a3 = *(const svec8*)(ldsA + ((w * 16 + (KT)) << 9) + l * 8); \
    acc[0] = MFMA16(af[KT][0], sb, acc[0], 0, 0, 0); \
    acc[1] = MFMA16(af[KT][1], sb, acc[1], 0, 0, 0); \
    acc[2] = MFMA16(af[KT][2], sb, acc[2], 0, 0, 0); \
    acc[3] = MFMA16(a3,        sb, acc[3], 0, 0, 0); \
    __builtin_amdgcn_sched_barrier(0); \
} while (0)

// epilogue one mt: +bx (transient decode), relu, cvt_pk, ds_write st[q]
#define EP(MT) do { \
    unsigned long long _u = bq[MT]; \
    float _f0 = fmaxf(acc[MT][0] + bf2f((unsigned short)( _u        & 0xffffu)), 0.0f); \
    float _f1 = fmaxf(acc[MT][1] + bf2f((unsigned short)((_u >> 16) & 0xffffu)), 0.0f); \
    float _f2 = fmaxf(acc[MT][2] + bf2f((unsigned short)((_u >> 32) & 0xffffu)), 0.0f); \
    float _f3 = fmaxf(acc[MT][3] + bf2f((unsigned short)((_u >> 48) & 0xffffu)), 0.0f); \
    unsigned int _plo, _phi; \
    asm("v_cvt_pk_bf16_f32 %0, %1, %2" : "=v"(_plo) : "v"(_f0), "v"(_f1)); \
    asm("v_cvt_pk_bf16_f32 %0, %1, %2" : "=v"(_phi) : "v"(_f2), "v"(_f3)); \
    uivec2 _ov; _ov[0] = _plo; _ov[1] = _phi; \
    *(uivec2*)(stq + ((2 * (nbase + 16 * (MT) + 4 * g)) ^ swz)) = _ov; \
} while (0)

__global__ __launch_bounds__(512, 2)
void recur1cu_kernel(const unsigned short* __restrict__ Abf,   // [512][512] bf16, A[n][k]
                     const unsigned short* __restrict__ bx,    // [65536][512] bf16, row = t*16+b
                     unsigned short* __restrict__ states)      // [65536][512] bf16, row = t*16+b
{
    __shared__ __align__(16) unsigned short st[2][16 * 512];     // 32 KB state dbuf, XOR-swizzled
    __shared__ __align__(16) unsigned short ldsA[8 * 16 * 512];  // 128 KB: [w][kt][frag 1KB], mt3
    const int tid = threadIdx.x;
    const int w = tid >> 6, l = tid & 63;
    const int g = l >> 4, r16 = l & 15;
    const int nbase = w * 64;
    const int swz = (r16 & 7) << 4;

    // ---- stage A mt=3 into LDS, fragment-linear ----
    #pragma unroll
    for (int kt = 0; kt < 16; ++kt) {
        usvec8 v = *(const usvec8*)(Abf + (size_t)(nbase + 48 + r16) * 512 + 32 * kt + 8 * g);
        *(usvec8*)(ldsA + ((w * 16 + kt) << 9) + l * 8) = v;
    }

    // ---- preload A mt=0..2 into plain registers: 48 frags = 192 regs ----
    svec8 af[16][3];
    #pragma unroll
    for (int kt = 0; kt < 16; ++kt)
        #pragma unroll
        for (int mt = 0; mt < 3; ++mt)
            af[kt][mt] = *(const svec8*)(Abf + (size_t)(nbase + 16 * mt + r16) * 512
                                         + 32 * kt + 8 * g);

    // ---- t = 0: state0 = relu(bx[0]) -> st[0] own 64 cols ----
    {
        const unsigned short* bp = bx + (size_t)r16 * 512 + nbase + 4 * g;
        char* st0 = (char*)&st[0][0] + r16 * 1024;
        #pragma unroll
        for (int mt = 0; mt < 4; ++mt) {
            unsigned long long u = *(const unsigned long long*)(bp + 16 * mt);
            float f0 = fmaxf(bf2f((unsigned short)( u        & 0xffffu)), 0.0f);
            float f1 = fmaxf(bf2f((unsigned short)((u >> 16) & 0xffffu)), 0.0f);
            float f2 = fmaxf(bf2f((unsigned short)((u >> 32) & 0xffffu)), 0.0f);
            float f3 = fmaxf(bf2f((unsigned short)((u >> 48) & 0xffffu)), 0.0f);
            unsigned int plo, phi;
            asm("v_cvt_pk_bf16_f32 %0, %1, %2" : "=v"(plo) : "v"(f0), "v"(f1));
            asm("v_cvt_pk_bf16_f32 %0, %1, %2" : "=v"(phi) : "v"(f2), "v"(f3));
            uivec2 ov; ov[0] = plo; ov[1] = phi;
            *(uivec2*)(st0 + ((2 * (nbase + 16 * mt + 4 * g)) ^ swz)) = ov;
        }
    }
    __syncthreads();

    // export lane mapping: wave w exports state rows {2w, 2w+1}; 32 lanes x 16B per half-row
    const int erow = 2 * w + (l >> 5);
    const int eswz = (erow & 7) << 4;
    const int ecol = (l & 31) * 16;

    #pragma unroll 1
    for (int t = 1; t < RT; ++t) {
        const char* stbase_p = (const char*)&st[(t - 1) & 1][0];
        char* stq = (char*)&st[t & 1][0] + r16 * 1024;

        // A) coalesced export of state_{t-1}; store drain overlaps MFMA region
        {
            const char* sp = stbase_p + erow * 1024;
            char* gp = (char*)states + ((size_t)(t - 1) * 16 + erow) * 1024 + ecol;
            #pragma unroll
            for (int jj = 0; jj < 2; ++jj) {
                uivec4 v = *(const uivec4*)(sp + ((ecol + 512 * jj) ^ eswz));
                *(uivec4*)(gp + 512 * jj) = v;
            }
        }

        // B) bx[t] loads (decoded transiently inside EP)
        unsigned long long bq[4];
        {
            const unsigned short* bp = bx + ((size_t)t * 16 + r16) * 512 + nbase + 4 * g;
            #pragma unroll
            for (int mt = 0; mt < 4; ++mt)
                bq[mt] = *(const unsigned long long*)(bp + 16 * mt);
        }

        // C) MFMA train: 16 kt x 4 intrinsic MFMAs, reads st[p]
        fvec4 acc[4];
        #pragma unroll
        for (int mt = 0; mt < 4; ++mt) acc[mt] = fvec4{0.f, 0.f, 0.f, 0.f};

        const char* stp = stbase_p + r16 * 1024;
        KTSTEP(0);  KTSTEP(1);  KTSTEP(2);  KTSTEP(3);
        KTSTEP(4);  KTSTEP(5);  KTSTEP(6);  KTSTEP(7);
        KTSTEP(8);  KTSTEP(9);  KTSTEP(10); KTSTEP(11);
        KTSTEP(12); KTSTEP(13); KTSTEP(14); KTSTEP(15);

        // D) epilogue: + bx, relu, cvt_pk, write st[q] own cols
        EP(0); EP(1); EP(2); EP(3);

        __syncthreads();   // st[q] complete; st[p] free for overwrite next iteration
    }

    // ---- final export: state_{RT-1} from st[(RT-1)&1] ----
    {
        const char* sp = (const char*)&st[(RT - 1) & 1][0] + erow * 1024;
        char* gp = (char*)states + ((size_t)(RT - 1) * 16 + erow) * 1024 + ecol;
        #pragma unroll
        for (int jj = 0; jj < 2; ++jj) {
            uivec4 v = *(const uivec4*)(sp + ((ecol + 512 * jj) ^ eswz));
            *(uivec4*)(gp + 512 * jj) = v;
        }
    }
}

extern "C" void kernel_launch(void* const* d_in, const int* in_sizes, int n_in,
                              void* d_out, int out_size, void* d_ws, size_t ws_size,
                              hipStream_t stream) {
    const float* x = (const float*)d_in[0];   // [16][4096][512]
    const float* A = (const float*)d_in[1];   // [512][512]
    const float* B = (const float*)d_in[2];   // [512][512]
    const float* C = (const float*)d_in[3];   // [512][512]
    float* out = (float*)d_out;               // [16][4096][512]

    char* ws = (char*)d_ws;
    unsigned short* Abf = (unsigned short*)(ws + 0);                          // 512KB
    unsigned short* Bbf = (unsigned short*)(ws + (size_t)(1 << 19));          // 512KB
    unsigned short* Cbf = (unsigned short*)(ws + (size_t)(2 << 19));          // 512KB
    unsigned short* bx  = (unsigned short*)(ws + (size_t)(4 << 19));          // 64MB: [65536][512] bf16
    unsigned short* states = (unsigned short*)(ws + (size_t)(4 << 19) + ((size_t)1 << 26)); // 64MB

    cvt_kernel<<<64, 256, 0, stream>>>(A, Abf, 512 * 512 / 4);
    cvt_kernel<<<64, 256, 0, stream>>>(B, Bbf, 512 * 512 / 4);
    cvt_kernel<<<64, 256, 0, stream>>>(C, Cbf, 512 * 512 / 4);

    dim3 grid(1024, 8);
    // bx[t*16+b][n] = sum_d x[b][t][d] * B[n][d]
    gemm512<true, false><<<grid, 256, 0, stream>>>((const void*)x, Bbf, (void*)bx);
    // sequential recurrence on one CU, 8 waves, states[t*16+b][n]
    recur1cu_kernel<<<1, 512, 0, stream>>>(Abf, bx, states);
    // y[b][t][j] = sum_n states[t*16+b][n] * C[j][n]
    gemm512<false, true><<<grid, 256, 0, stream>>>((const void*)states, Cbf, (void*)out);
}